// Round 3
// baseline (117.627 us; speedup 1.0000x reference)
//
#include <hip/hip_runtime.h>

// B=2, S=2048, D=512, K_routes=64, H=8 (heads irrelevant: k-weighted sum is head-uniform)
#define S_DIM 2048
#define D_DIM 512
#define K_RT  64
#define M_DIM 4096   // B*S

#define GBM 64
#define GBN 64
#define GBK 64

typedef __attribute__((ext_vector_type(8))) short short8;   // 8 bf16 = 4 VGPRs (MFMA A/B frag)
typedef __attribute__((ext_vector_type(4))) float f32x4;    // MFMA C/D frag
typedef unsigned int u32;
#define AS1 __attribute__((address_space(1)))
#define AS3 __attribute__((address_space(3)))

static __device__ __forceinline__ float bf16lo_to_f(unsigned u) {
    union { unsigned u; float f; } c; c.u = u << 16; return c.f;
}
static __device__ __forceinline__ float bf16hi_to_f(unsigned u) {
    union { unsigned u; float f; } c; c.u = u & 0xffff0000u; return c.f;
}
static __device__ __forceinline__ unsigned short f_to_bf16(float f) {
    union { float f; unsigned u; } c; c.f = f;
    unsigned u = c.u;
    u += 0x7fffu + ((u >> 16) & 1u);   // RTNE (inputs finite/normal)
    return (unsigned short)(u >> 16);
}
static __device__ __forceinline__ unsigned pk2(float a, float b) {
    return (unsigned)f_to_bf16(a) | ((unsigned)f_to_bf16(b) << 16);
}
static __device__ __forceinline__ short8 pack8(float4 a, float4 b) {
    union { short8 s; unsigned u[4]; } r;
    r.u[0] = pk2(a.x, a.y); r.u[1] = pk2(a.z, a.w);
    r.u[2] = pk2(b.x, b.y); r.u[3] = pk2(b.z, b.w);
    return r.s;
}

// ---------------------------------------------------------------------------
// C = A * B^T (M=4096, N=K=512), MFMA bf16, double-buffered 2-phase pipeline.
// NEW: fp32 operands are cast to bf16 IN the staging path (global float4 ->
// v_cvt pack -> ds_write_b128 into the same 32-k/64-B-row panel layout), so
// the former prep_cast pass and its workspace round-trip disappear.
//   AF32=true : A staged from fp32 (x), B staged from fp32 (W_in)   [gemm1]
//   AF32=false: A via global_load_lds from bf16 (fb), B from fp32 W [gemm2]
// Per K-step: issue t+1 loads BEFORE t's MFMAs (latency hides under compute),
// cvt+ds_write after, ONE barrier per step. Buffer hazard: writes to buf^1 in
// step t are safe (its readers finished before the barrier ending step t-1).
// Chunked XCD swizzle: bid&7 = XCD -> row-tiles [8p,8p+8) x all 8 col-tiles.
template<bool OUTF32, bool AF32>
__global__ __launch_bounds__(256) void gemm_bt(
    const void* __restrict__ Av,     // AF32 ? fp32 MxK : bf16 MxK
    const float* __restrict__ Bf,    // N x K fp32 weights
    void* __restrict__ Cv,
    const float* __restrict__ bias, const float* __restrict__ residual)
{
    __shared__ unsigned short As[4][GBM * 32];   // [buf*2+panel], 16 KB
    __shared__ unsigned short Bs[4][GBN * 32];   // 16 KB

    const int N = D_DIM, K = D_DIM;
    const int tid  = threadIdx.x;
    const int lane = tid & 63;
    const int wv   = tid >> 6;
    const int bid  = blockIdx.x;              // 0..511
    const int within = bid >> 3;              // 0..63
    const int m0 = ((bid & 7) * 8 + (within >> 3)) * GBM;
    const int n0 = (within & 7) * GBN;
    const int wm = (wv & 1) * 32;
    const int wn = (wv >> 1) * 32;

    // reg-staging geometry (fp32 sources): wave wv covers rows [wv*16,+16);
    // lane = 4 lanes/row, lane's k-chunk = c*16..c*16+16 floats -> 16 bf16
    // landing in panel c>>1 at k-offset (c&1)*16 (two ds_write_b128).
    const int srow = wv * 16 + (lane >> 2);
    const int c    = lane & 3;
    const int kh_w = c >> 1;
    const int kb_w = (c & 1) * 16;
    const float* Bsrc = Bf + (size_t)(n0 + srow) * K + c * 16;
    const float* Asrc = AF32 ? ((const float*)Av + (size_t)(m0 + srow) * K + c * 16) : nullptr;
    // bf16-A DMA geometry (wave-uniform base + lane*16B contract)
    const unsigned short* Arow16 = AF32 ? nullptr :
        ((const unsigned short*)Av + (size_t)(m0 + srow) * K + (lane & 3) * 8);

    const int mi = lane & 15;
    const int kg = lane >> 4;

    f32x4 acc[2][2] = {};

#define LOAD4(dst, src, k0) do {                       \
    dst[0] = *(const float4*)((src) + (k0));           \
    dst[1] = *(const float4*)((src) + (k0) + 4);       \
    dst[2] = *(const float4*)((src) + (k0) + 8);       \
    dst[3] = *(const float4*)((src) + (k0) + 12);      \
} while (0)
#define WR8(panelArr, buf, regs) do {                                                        \
    *(short8*)(panelArr[(buf)*2 + kh_w] + srow * 32 + kb_w)     = pack8(regs[0], regs[1]);   \
    *(short8*)(panelArr[(buf)*2 + kh_w] + srow * 32 + kb_w + 8) = pack8(regs[2], regs[3]);   \
} while (0)
#define DMA_A(buf, k0) do {                                                              \
    __builtin_amdgcn_global_load_lds((const AS1 u32*)(Arow16 + (k0)),                    \
                                     (AS3 u32*)(As[(buf)*2 + 0] + wv * 512), 16, 0, 0);  \
    __builtin_amdgcn_global_load_lds((const AS1 u32*)(Arow16 + (k0) + 32),               \
                                     (AS3 u32*)(As[(buf)*2 + 1] + wv * 512), 16, 0, 0);  \
} while (0)

    // prologue: stage K-step 0 into buf 0
    {
        float4 ar[4], br[4];
        if constexpr (AF32) LOAD4(ar, Asrc, 0); else DMA_A(0, 0);
        LOAD4(br, Bsrc, 0);
        if constexpr (AF32) WR8(As, 0, ar);
        WR8(Bs, 0, br);
        __syncthreads();
    }

    #pragma unroll
    for (int t = 0; t < K / GBK; ++t) {      // 8 steps, fully unrolled
        const int cur = t & 1;
        float4 ar[4], br[4];
        if (t + 1 < K / GBK) {               // issue next-step loads early
            const int k0n = (t + 1) * GBK;
            if constexpr (AF32) LOAD4(ar, Asrc, k0n); else DMA_A(cur ^ 1, k0n);
            LOAD4(br, Bsrc, k0n);
        }
        #pragma unroll
        for (int kh = 0; kh < 2; ++kh) {
            short8 af0 = *(const short8*)(As[cur*2 + kh] + (wm +      mi) * 32 + kg * 8);
            short8 af1 = *(const short8*)(As[cur*2 + kh] + (wm + 16 + mi) * 32 + kg * 8);
            short8 bf0 = *(const short8*)(Bs[cur*2 + kh] + (wn +      mi) * 32 + kg * 8);
            short8 bf1 = *(const short8*)(Bs[cur*2 + kh] + (wn + 16 + mi) * 32 + kg * 8);

            acc[0][0] = __builtin_amdgcn_mfma_f32_16x16x32_bf16(af0, bf0, acc[0][0], 0, 0, 0);
            acc[0][1] = __builtin_amdgcn_mfma_f32_16x16x32_bf16(af0, bf1, acc[0][1], 0, 0, 0);
            acc[1][0] = __builtin_amdgcn_mfma_f32_16x16x32_bf16(af1, bf0, acc[1][0], 0, 0, 0);
            acc[1][1] = __builtin_amdgcn_mfma_f32_16x16x32_bf16(af1, bf1, acc[1][1], 0, 0, 0);
        }
        if (t + 1 < K / GBK) {               // cvt + LDS-write next step
            if constexpr (AF32) WR8(As, cur ^ 1, ar);
            WR8(Bs, cur ^ 1, br);
        }
        __syncthreads();                     // drains vmcnt + lgkmcnt
    }
#undef LOAD4
#undef WR8
#undef DMA_A

    // C/D layout: col = lane&15, row = (lane>>4)*4 + reg   [verified m89/m91]
    const int rb  = (lane >> 4) * 4;
    const int col = lane & 15;
    #pragma unroll
    for (int i = 0; i < 2; ++i) {
        #pragma unroll
        for (int j = 0; j < 2; ++j) {
            #pragma unroll
            for (int r = 0; r < 4; ++r) {
                const int m = m0 + wm + i * 16 + rb + r;
                const int n = n0 + wn + j * 16 + col;
                const float v = acc[i][j][r];
                if (OUTF32) {
                    ((float*)Cv)[(size_t)m * N + n] = v + bias[n] + residual[(size_t)m * N + n];
                } else {
                    ((unsigned short*)Cv)[(size_t)m * N + n] = f_to_bf16(v);
                }
            }
        }
    }
}

// ---------------------------------------------------------------------------
// fused[b,s,:] = sum_k softmax_k(-dist[s,routes[s,k]]) * h[b,routes[s,k],:]
// One wave per (b,s); lane k owns route_k; in-wave shfl softmax; k-loop split
// into TWO interleaved chains (k, k+32) for 2x load ILP, v_readlane -> SGPR
// route/weight (scalar row base, SALU), loop-invariant vector offset lane*16B.
// __launch_bounds__(256,4) caps VGPR at 128. b = bx&1 aligns b with XCD
// parity so each XCD's L2 holds mostly one b's 2 MB h-slice.
__global__ __launch_bounds__(256, 4) void fuse_gather(
    const unsigned short* __restrict__ h, const int* __restrict__ routes,
    const float* __restrict__ distances, unsigned short* __restrict__ fused)
{
    const int tid  = threadIdx.x;
    const int lane = tid & 63;
    const int wv   = tid >> 6;
    const int bx   = blockIdx.x;        // 0..1023
    const int b    = bx & 1;
    const int s    = (bx >> 1) * 4 + wv;

    const int rt = routes[s * K_RT + lane];
    const float v = -distances[(size_t)s * S_DIM + rt];
    float mx = v;
    #pragma unroll
    for (int off = 32; off >= 1; off >>= 1) mx = fmaxf(mx, __shfl_xor(mx, off, 64));
    const float e = __expf(v - mx);
    float sum = e;
    #pragma unroll
    for (int off = 32; off >= 1; off >>= 1) sum += __shfl_xor(sum, off, 64);
    const float wl = e / sum;

    const unsigned short* hb = h + (size_t)b * S_DIM * D_DIM;
    float acc0[8] = {}, acc1[8] = {};
    #pragma unroll
    for (int k = 0; k < 32; ++k) {
        const int   rk0 = __builtin_amdgcn_readlane(rt, k);
        const int   rk1 = __builtin_amdgcn_readlane(rt, k + 32);
        const float wk0 = __int_as_float(__builtin_amdgcn_readlane(__float_as_int(wl), k));
        const float wk1 = __int_as_float(__builtin_amdgcn_readlane(__float_as_int(wl), k + 32));
        const uint4 p0 = *(const uint4*)(hb + (size_t)rk0 * D_DIM + lane * 8);
        const uint4 p1 = *(const uint4*)(hb + (size_t)rk1 * D_DIM + lane * 8);
        acc0[0] = fmaf(wk0, bf16lo_to_f(p0.x), acc0[0]);
        acc0[1] = fmaf(wk0, bf16hi_to_f(p0.x), acc0[1]);
        acc0[2] = fmaf(wk0, bf16lo_to_f(p0.y), acc0[2]);
        acc0[3] = fmaf(wk0, bf16hi_to_f(p0.y), acc0[3]);
        acc0[4] = fmaf(wk0, bf16lo_to_f(p0.z), acc0[4]);
        acc0[5] = fmaf(wk0, bf16hi_to_f(p0.z), acc0[5]);
        acc0[6] = fmaf(wk0, bf16lo_to_f(p0.w), acc0[6]);
        acc0[7] = fmaf(wk0, bf16hi_to_f(p0.w), acc0[7]);
        acc1[0] = fmaf(wk1, bf16lo_to_f(p1.x), acc1[0]);
        acc1[1] = fmaf(wk1, bf16hi_to_f(p1.x), acc1[1]);
        acc1[2] = fmaf(wk1, bf16lo_to_f(p1.y), acc1[2]);
        acc1[3] = fmaf(wk1, bf16hi_to_f(p1.y), acc1[3]);
        acc1[4] = fmaf(wk1, bf16lo_to_f(p1.z), acc1[4]);
        acc1[5] = fmaf(wk1, bf16hi_to_f(p1.z), acc1[5]);
        acc1[6] = fmaf(wk1, bf16lo_to_f(p1.w), acc1[6]);
        acc1[7] = fmaf(wk1, bf16hi_to_f(p1.w), acc1[7]);
    }
    uint4 o;
    o.x = pk2(acc0[0] + acc1[0], acc0[1] + acc1[1]);
    o.y = pk2(acc0[2] + acc1[2], acc0[3] + acc1[3]);
    o.z = pk2(acc0[4] + acc1[4], acc0[5] + acc1[5]);
    o.w = pk2(acc0[6] + acc1[6], acc0[7] + acc1[7]);
    *(uint4*)(fused + ((size_t)b * S_DIM + s) * D_DIM + lane * 8) = o;
}

// ---------------------------------------------------------------------------
extern "C" void kernel_launch(void* const* d_in, const int* in_sizes, int n_in,
                              void* d_out, int out_size, void* d_ws, size_t ws_size,
                              hipStream_t stream) {
    const float* x         = (const float*)d_in[0];
    const int*   routes    = (const int*)  d_in[1];
    const float* distances = (const float*)d_in[2];
    const float* W_in      = (const float*)d_in[3];
    const float* W_out     = (const float*)d_in[4];
    const float* b_out     = (const float*)d_in[5];
    float* out = (float*)d_out;

    // ws layout (bf16 elems): h 4 MB | fb 4 MB
    unsigned short* hb = (unsigned short*)d_ws;
    unsigned short* fb = hb + (size_t)M_DIM * D_DIM;

    // 1. h = x @ W_in^T  (fp32 A and B cast in staging, bf16 out)
    gemm_bt<false, true><<<512, 256, 0, stream>>>((const void*)x, W_in, hb, nullptr, nullptr);
    // 2. softmax + gather + weighted sum (bf16 out), 2-chain ILP
    fuse_gather<<<dim3(1024), 256, 0, stream>>>(hb, routes, distances, fb);
    // 3. out = fused @ W_out^T + b_out + x  (bf16 A via DMA, fp32 B cast in
    //    staging, fp32 out + residual)
    gemm_bt<true, false><<<512, 256, 0, stream>>>((const void*)fb, W_out, out, b_out, x);
}

// Round 4
// 116.371 us; speedup vs baseline: 1.0108x; 1.0108x over previous
//
#include <hip/hip_runtime.h>
#include <hip/hip_bf16.h>

// B=2, S=2048, D=512, K_routes=64, H=8 (heads irrelevant: k-weighted sum is head-uniform)
#define S_DIM 2048
#define D_DIM 512
#define B_DIM 2
#define K_RT  64
#define M_DIM 4096   // B*S

typedef __attribute__((ext_vector_type(8))) short short8;   // 8 bf16 = 4 VGPRs (MFMA A/B frag)
typedef __attribute__((ext_vector_type(4))) float f32x4;    // MFMA C/D frag
typedef unsigned int u32;
#define AS1 __attribute__((address_space(1)))
#define AS3 __attribute__((address_space(3)))

static __device__ __forceinline__ float bf16lo_to_f(unsigned u) {
    union { unsigned u; float f; } c; c.u = u << 16; return c.f;
}
static __device__ __forceinline__ float bf16hi_to_f(unsigned u) {
    union { unsigned u; float f; } c; c.u = u & 0xffff0000u; return c.f;
}
static __device__ __forceinline__ unsigned short f_to_bf16(float f) {
    union { float f; unsigned u; } c; c.f = f;
    unsigned u = c.u;
    u += 0x7fffu + ((u >> 16) & 1u);   // RTNE (inputs finite/normal)
    return (unsigned short)(u >> 16);
}
static __device__ __forceinline__ unsigned pk2(float a, float b) {
    return (unsigned)f_to_bf16(a) | ((unsigned)f_to_bf16(b) << 16);
}

// ---------------------------------------------------------------------------
// prep: pure streaming cast x / W_in / W_out fp32 -> bf16 (float4 -> ushort4).
// Exact grid: (524288 + 2*65536) float4s / 256 = 2560 blocks.
__global__ __launch_bounds__(256) void prep_cast(
    const float* __restrict__ x, const float* __restrict__ Wi, const float* __restrict__ Wo,
    unsigned short* __restrict__ xb, unsigned short* __restrict__ wib,
    unsigned short* __restrict__ wob)
{
    const int g = blockIdx.x * 256 + threadIdx.x;    // one per float4
    const int NX = M_DIM * D_DIM / 4;                // 524288
    const int NW = D_DIM * D_DIM / 4;                // 65536
    const float* src; unsigned short* dst; int off;
    if (g < NX)           { src = x;  dst = xb;  off = g; }
    else if (g < NX + NW) { src = Wi; dst = wib; off = g - NX; }
    else                  { src = Wo; dst = wob; off = g - NX - NW; }
    const float4 v = ((const float4*)src)[off];
    ushort4 o;
    o.x = f_to_bf16(v.x); o.y = f_to_bf16(v.y);
    o.z = f_to_bf16(v.z); o.w = f_to_bf16(v.w);
    ((ushort4*)dst)[off] = o;
}

// ---------------------------------------------------------------------------
// C = A * B^T, pure bf16 operands, global_load_lds staging.
// 64x64 tile, BK=64 as two 32-k LDS panels (DMA contract: wave-uniform base
// + lane*16B, 64-B rows). ROUND-4 SINGLE CHANGE vs round-0: double-buffered
// panels with the next K-step's DMA issued BEFORE this step's MFMAs and ONE
// barrier per K-step (vmcnt(0) drain overlaps the MFMAs just issued),
// instead of stage -> drain -> compute with latency fully exposed.
// Everything else (2D grid, layouts, epilogue) identical to round-0.
#define GBM 64
#define GBN 64
#define GBK 64

template<bool OUTF32>
__global__ __launch_bounds__(256) void gemm_bt(
    const unsigned short* __restrict__ A,   // M x K bf16
    const unsigned short* __restrict__ B,   // N x K bf16
    void* __restrict__ Cv,
    const float* __restrict__ bias, const float* __restrict__ residual)
{
    __shared__ unsigned short As[4][GBM * 32];   // [buf*2+panel], 16 KB
    __shared__ unsigned short Bs[4][GBN * 32];   // 16 KB

    const int N = D_DIM, K = D_DIM;
    const int tid  = threadIdx.x;
    const int lane = tid & 63;
    const int wv   = tid >> 6;
    const int wm   = (wv & 1) * 32;
    const int wn   = (wv >> 1) * 32;
    const int m0   = blockIdx.y * GBM;
    const int n0   = blockIdx.x * GBN;

    // DMA staging: wave wv covers rows [wv*16, wv*16+16); per panel, lane l
    // sources row wv*16 + l/4, k-elems (l&3)*8..+8 -> LDS base + l*16 B.
    const int srow  = wv * 16 + (lane >> 2);
    const int skoff = (lane & 3) * 8;
    const unsigned short* Arow = A + (size_t)(m0 + srow) * K + skoff;
    const unsigned short* Brow = B + (size_t)(n0 + srow) * K + skoff;

    const int mi = lane & 15;
    const int kg = lane >> 4;

    f32x4 acc[2][2] = {};

#define STAGE(buf, k0) do {                                                              \
    __builtin_amdgcn_global_load_lds((const AS1 u32*)(Arow + (k0)),                      \
                                     (AS3 u32*)(As[(buf)*2 + 0] + wv * 512), 16, 0, 0);  \
    __builtin_amdgcn_global_load_lds((const AS1 u32*)(Arow + (k0) + 32),                 \
                                     (AS3 u32*)(As[(buf)*2 + 1] + wv * 512), 16, 0, 0);  \
    __builtin_amdgcn_global_load_lds((const AS1 u32*)(Brow + (k0)),                      \
                                     (AS3 u32*)(Bs[(buf)*2 + 0] + wv * 512), 16, 0, 0);  \
    __builtin_amdgcn_global_load_lds((const AS1 u32*)(Brow + (k0) + 32),                 \
                                     (AS3 u32*)(Bs[(buf)*2 + 1] + wv * 512), 16, 0, 0);  \
} while (0)

    STAGE(0, 0);
    __syncthreads();           // drain prologue DMA

    #pragma unroll
    for (int t = 0; t < K / GBK; ++t) {      // K compile-time -> full unroll
        const int cur = t & 1;
        if (t + 1 < K / GBK) STAGE(cur ^ 1, (t + 1) * GBK);   // prefetch next
        #pragma unroll
        for (int kh = 0; kh < 2; ++kh) {
            short8 af0 = *(const short8*)(As[cur*2 + kh] + (wm +      mi) * 32 + kg * 8);
            short8 af1 = *(const short8*)(As[cur*2 + kh] + (wm + 16 + mi) * 32 + kg * 8);
            short8 bf0 = *(const short8*)(Bs[cur*2 + kh] + (wn +      mi) * 32 + kg * 8);
            short8 bf1 = *(const short8*)(Bs[cur*2 + kh] + (wn + 16 + mi) * 32 + kg * 8);

            acc[0][0] = __builtin_amdgcn_mfma_f32_16x16x32_bf16(af0, bf0, acc[0][0], 0, 0, 0);
            acc[0][1] = __builtin_amdgcn_mfma_f32_16x16x32_bf16(af0, bf1, acc[0][1], 0, 0, 0);
            acc[1][0] = __builtin_amdgcn_mfma_f32_16x16x32_bf16(af1, bf0, acc[1][0], 0, 0, 0);
            acc[1][1] = __builtin_amdgcn_mfma_f32_16x16x32_bf16(af1, bf1, acc[1][1], 0, 0, 0);
        }
        __syncthreads();       // drains prefetch (overlapped with MFMAs above)
    }
#undef STAGE

    // C/D layout: col = lane&15, row = (lane>>4)*4 + reg   [verified m89/m91]
    const int rb  = (lane >> 4) * 4;
    const int col = lane & 15;
    #pragma unroll
    for (int i = 0; i < 2; ++i) {
        #pragma unroll
        for (int j = 0; j < 2; ++j) {
            #pragma unroll
            for (int r = 0; r < 4; ++r) {
                const int m = m0 + wm + i * 16 + rb + r;
                const int n = n0 + wn + j * 16 + col;
                const float v = acc[i][j][r];
                if (OUTF32) {
                    ((float*)Cv)[(size_t)m * N + n] = v + bias[n] + residual[(size_t)m * N + n];
                } else {
                    ((unsigned short*)Cv)[(size_t)m * N + n] = f_to_bf16(v);
                }
            }
        }
    }
}

// ---------------------------------------------------------------------------
// fused[b,s,:] = sum_k softmax_k(-dist[s,routes[s,k]]) * h[b,routes[s,k],:]
// One wave per (b,s): lane k owns route_k; in-wave shfl softmax; then full
// unroll over k with v_readlane -> SGPR route/weight (scalar row base, SALU),
// loop-invariant vector offset lane*16B. b = bx&1 aligns b with XCD parity so
// each XCD's 4 MiB L2 holds mostly one b's h-slice. (Identical to round-0.)
__global__ __launch_bounds__(256) void fuse_gather(
    const unsigned short* __restrict__ h, const int* __restrict__ routes,
    const float* __restrict__ distances, unsigned short* __restrict__ fused)
{
    const int tid  = threadIdx.x;
    const int lane = tid & 63;
    const int wv   = tid >> 6;
    const int bx   = blockIdx.x;        // 0..1023
    const int b    = bx & 1;
    const int s    = (bx >> 1) * 4 + wv;

    const int rt = routes[s * K_RT + lane];
    const float v = -distances[(size_t)s * S_DIM + rt];
    float mx = v;
    #pragma unroll
    for (int off = 32; off >= 1; off >>= 1) mx = fmaxf(mx, __shfl_xor(mx, off, 64));
    const float e = __expf(v - mx);
    float sum = e;
    #pragma unroll
    for (int off = 32; off >= 1; off >>= 1) sum += __shfl_xor(sum, off, 64);
    const float wl = e / sum;

    const unsigned short* hb = h + (size_t)b * S_DIM * D_DIM;
    float acc[8] = {};
    #pragma unroll
    for (int k = 0; k < 64; ++k) {
        const int   rk = __builtin_amdgcn_readlane(rt, k);
        const float wk = __int_as_float(__builtin_amdgcn_readlane(__float_as_int(wl), k));
        const uint4 p = *(const uint4*)(hb + (size_t)rk * D_DIM + lane * 8);
        acc[0] = fmaf(wk, bf16lo_to_f(p.x), acc[0]);
        acc[1] = fmaf(wk, bf16hi_to_f(p.x), acc[1]);
        acc[2] = fmaf(wk, bf16lo_to_f(p.y), acc[2]);
        acc[3] = fmaf(wk, bf16hi_to_f(p.y), acc[3]);
        acc[4] = fmaf(wk, bf16lo_to_f(p.z), acc[4]);
        acc[5] = fmaf(wk, bf16hi_to_f(p.z), acc[5]);
        acc[6] = fmaf(wk, bf16lo_to_f(p.w), acc[6]);
        acc[7] = fmaf(wk, bf16hi_to_f(p.w), acc[7]);
    }
    uint4 o;
    o.x = pk2(acc[0], acc[1]);
    o.y = pk2(acc[2], acc[3]);
    o.z = pk2(acc[4], acc[5]);
    o.w = pk2(acc[6], acc[7]);
    *(uint4*)(fused + ((size_t)b * S_DIM + s) * D_DIM + lane * 8) = o;
}

// ---------------------------------------------------------------------------
extern "C" void kernel_launch(void* const* d_in, const int* in_sizes, int n_in,
                              void* d_out, int out_size, void* d_ws, size_t ws_size,
                              hipStream_t stream) {
    const float* x         = (const float*)d_in[0];
    const int*   routes    = (const int*)  d_in[1];
    const float* distances = (const float*)d_in[2];
    const float* W_in      = (const float*)d_in[3];
    const float* W_out     = (const float*)d_in[4];
    const float* b_out     = (const float*)d_in[5];
    float* out = (float*)d_out;

    // ws layout (bf16 elems): xb 2M | wib 256K | wob 256K | h 2M | fb 2M = 13 MB
    unsigned short* xb  = (unsigned short*)d_ws;
    unsigned short* wib = xb  + (size_t)M_DIM * D_DIM;
    unsigned short* wob = wib + (size_t)D_DIM * D_DIM;
    unsigned short* hb  = wob + (size_t)D_DIM * D_DIM;
    unsigned short* fb  = hb  + (size_t)M_DIM * D_DIM;

    const dim3 ggrid(D_DIM / GBN, M_DIM / GBM);   // 8 x 64 = 512 blocks

    // 1. streaming bf16 casts (exact grid)
    prep_cast<<<2560, 256, 0, stream>>>(x, W_in, W_out, xb, wib, wob);
    // 2. h = x @ W_in^T  (bf16 out), dbuf-prefetch K-loop
    gemm_bt<false><<<ggrid, 256, 0, stream>>>(xb, wib, hb, nullptr, nullptr);
    // 3. softmax + gather + weighted sum (bf16 out)
    fuse_gather<<<dim3(1024), 256, 0, stream>>>(hb, routes, distances, fb);
    // 4. out = fused @ W_out^T + b_out + x  (fp32 out + residual)
    gemm_bt<true><<<ggrid, 256, 0, stream>>>(fb, wob, out, b_out, x);
}